// Round 3
// baseline (197.237 us; speedup 1.0000x reference)
//
#include <hip/hip_runtime.h>
#include <hip/hip_bf16.h>

// ViT embed: patchify + linear + cls + posemb + LayerNorm, fused.
// images [128,3,224,224] f32 -> out [128,197,768] f32.
// M = 128*196 = 25088 patch-rows, K = 768, N = 768.
// v3: barrier-free K-loop. A-fragments loaded DIRECTLY from global images
// (lane (l15,g) needs rows l15, k=g*8..g*8+7 = 8 contiguous pixels = 32B),
// cvt_pk to bf16 in-register. No LDS in the main loop, no barriers, full
// unroll; B from L2-resident bf16 W with immediate-offset addressing.
// Block = 32 rows x 768 cols, 4 waves (wave = 2mf x 12nf), grid = 784.

#define IMG_B 128
#define IMG_C 3
#define IMG_HW 224
#define DTOK 768
#define NTOK 197
#define MROWS 25088

typedef __attribute__((ext_vector_type(4))) float f32x4;
typedef __attribute__((ext_vector_type(8))) short bf16x8;

__device__ __forceinline__ unsigned short f2b(float f) {
  union { float f; unsigned u; } v; v.f = f;
  unsigned u = v.u;
  return (unsigned short)((u + 0x7fffu + ((u >> 16) & 1u)) >> 16);
}

// ---------------- setup kernels ----------------

__global__ void conv_w(const float* __restrict__ W, unsigned short* __restrict__ Wb) {
  int i = blockIdx.x * 256 + threadIdx.x;
  if (i < DTOK * DTOK) Wb[i] = f2b(W[i]);
}

// bpos[t][d] = pos(t,d) + (t==0 ? cls[d] : bias[d])
__global__ void make_bpos(const float* __restrict__ bias, const float* __restrict__ cls,
                          float* __restrict__ bpos) {
  int i = blockIdx.x * 256 + threadIdx.x;
  if (i >= NTOK * DTOK) return;
  int t = i / DTOK, d = i - (i / DTOK) * DTOK;
  float expo = (float)(d & ~1) * (1.0f / (float)DTOK);
  float angle = (float)t * exp2f(-expo * 13.287712379549449f);
  float pv = (d & 1) ? cosf(angle) : sinf(angle);
  bpos[i] = pv + ((t == 0) ? cls[d] : bias[d]);
}

// token-0 row: LN(cls + pos[0]) broadcast to all 128 batches
__global__ __launch_bounds__(256) void cls_kernel(const float* __restrict__ bpos,
                                                  const float* __restrict__ gamma,
                                                  const float* __restrict__ beta,
                                                  float* __restrict__ out) {
  __shared__ float sred[8];
  const int tid = threadIdx.x;
  float v0 = bpos[tid], v1 = bpos[tid + 256], v2 = bpos[tid + 512];
  float s1 = v0 + v1 + v2;
  float s2 = v0 * v0 + v1 * v1 + v2 * v2;
  #pragma unroll
  for (int off = 32; off >= 1; off >>= 1) {
    s1 += __shfl_xor(s1, off, 64);
    s2 += __shfl_xor(s2, off, 64);
  }
  if ((tid & 63) == 0) { sred[(tid >> 6) * 2] = s1; sred[(tid >> 6) * 2 + 1] = s2; }
  __syncthreads();
  float S1 = sred[0] + sred[2] + sred[4] + sred[6];
  float S2 = sred[1] + sred[3] + sred[5] + sred[7];
  float mean = S1 * (1.0f / 768.0f);
  float rstd = rsqrtf(S2 * (1.0f / 768.0f) - mean * mean + 1e-5f);
  float o0 = (v0 - mean) * rstd * gamma[tid] + beta[tid];
  float o1 = (v1 - mean) * rstd * gamma[tid + 256] + beta[tid + 256];
  float o2 = (v2 - mean) * rstd * gamma[tid + 512] + beta[tid + 512];
  for (int b = 0; b < IMG_B; ++b) {
    float* op = out + (size_t)b * NTOK * DTOK;
    op[tid] = o0; op[tid + 256] = o1; op[tid + 512] = o2;
  }
}

// ---------------- main fused kernel ----------------

__global__ __launch_bounds__(256, 2) void vit_main(
    const float* __restrict__ images, const unsigned short* __restrict__ Wb,
    const float* __restrict__ bpos, const float* __restrict__ gamma,
    const float* __restrict__ beta, float* __restrict__ out) {
  __shared__ float red[4][32][2];
  __shared__ float rowstat[32][2];

  const int tid = threadIdx.x;
  const int wq = tid >> 6;        // wave id = n-slice 0..3
  const int lane = tid & 63;
  const int l15 = lane & 15;
  const int g = lane >> 4;
  const int blk = blockIdx.x;
  const int cbase = wq * 192;

  // A row base pointers (mf = 0,1): row m = blk*32 + mf*16 + l15.
  // Lane covers k = g*8..g*8+7 -> fold pw = (g&1)*8 into the base; the
  // remaining per-iter offset is idx = it*2 + (g>>1): c = idx>>4, ph = idx&15.
  const float* abase[2];
  #pragma unroll
  for (int mf = 0; mf < 2; ++mf) {
    const int m = blk * 32 + mf * 16 + l15;
    const int sb = m / 196;
    const int sp = m - sb * 196;
    const int spy = sp / 14, spx = sp - (sp / 14) * 14;
    abase[mf] = images + (size_t)sb * (IMG_C * IMG_HW * IMG_HW) +
                (spy * 16) * IMG_HW + spx * 16 + (g & 1) * 8;
  }
  const int gb = g >> 1;

  // B per-lane base per nf; per-iter k advance = 32 shorts = 64 B (imm-foldable)
  const unsigned short* bbase[12];
  #pragma unroll
  for (int nf = 0; nf < 12; ++nf)
    bbase[nf] = Wb + (size_t)(cbase + nf * 16 + l15) * DTOK + g * 8;

  f32x4 acc[2][12];
  #pragma unroll
  for (int mf = 0; mf < 2; ++mf)
    #pragma unroll
    for (int nf = 0; nf < 12; ++nf)
      acc[mf][nf] = (f32x4)(0.0f);

  #pragma unroll
  for (int it = 0; it < 24; ++it) {
    const int idx = it * 2 + gb;
    const int aoff = (idx >> 4) * (IMG_HW * IMG_HW) + (idx & 15) * IMG_HW;

    bf16x8 afr[2];
    #pragma unroll
    for (int mf = 0; mf < 2; ++mf) {
      const float4 v0 = *(const float4*)(abase[mf] + aoff);
      const float4 v1 = *(const float4*)(abase[mf] + aoff + 4);
      union { __hip_bfloat162 h2[4]; bf16x8 v; } u;
      u.h2[0] = __float22bfloat162_rn(make_float2(v0.x, v0.y));
      u.h2[1] = __float22bfloat162_rn(make_float2(v0.z, v0.w));
      u.h2[2] = __float22bfloat162_rn(make_float2(v1.x, v1.y));
      u.h2[3] = __float22bfloat162_rn(make_float2(v1.z, v1.w));
      afr[mf] = u.v;
    }

    #pragma unroll
    for (int nf = 0; nf < 12; ++nf) {
      const bf16x8 bf = *(const bf16x8*)(bbase[nf] + it * 32);
      acc[0][nf] = __builtin_amdgcn_mfma_f32_16x16x32_bf16(afr[0], bf, acc[0][nf], 0, 0, 0);
      acc[1][nf] = __builtin_amdgcn_mfma_f32_16x16x32_bf16(afr[1], bf, acc[1][nf], 0, 0, 0);
    }
  }

  // ---- epilogue: +bias+pos, row LN over full 768 ----
  float s1[8], s2[8];
  #pragma unroll
  for (int mf = 0; mf < 2; ++mf) {
    #pragma unroll
    for (int r = 0; r < 4; ++r) {
      const int rl = mf * 16 + g * 4 + r;
      const int m = blk * 32 + rl;
      const int trow = 1 + (m % 196);
      const float* bp = bpos + (size_t)trow * DTOK + cbase + l15;
      float a1 = 0.f, a2 = 0.f;
      #pragma unroll
      for (int nf = 0; nf < 12; ++nf) {
        float val = acc[mf][nf][r] + bp[nf * 16];
        acc[mf][nf][r] = val;
        a1 += val; a2 += val * val;
      }
      s1[mf * 4 + r] = a1; s2[mf * 4 + r] = a2;
    }
  }
  #pragma unroll
  for (int off = 8; off >= 1; off >>= 1) {
    #pragma unroll
    for (int i = 0; i < 8; ++i) {
      s1[i] += __shfl_xor(s1[i], off, 64);
      s2[i] += __shfl_xor(s2[i], off, 64);
    }
  }
  if (l15 == 0) {
    #pragma unroll
    for (int mf = 0; mf < 2; ++mf)
      #pragma unroll
      for (int r = 0; r < 4; ++r) {
        const int rl = mf * 16 + g * 4 + r;
        red[wq][rl][0] = s1[mf * 4 + r];
        red[wq][rl][1] = s2[mf * 4 + r];
      }
  }
  __syncthreads();
  if (tid < 32) {
    float S1 = red[0][tid][0] + red[1][tid][0] + red[2][tid][0] + red[3][tid][0];
    float S2 = red[0][tid][1] + red[1][tid][1] + red[2][tid][1] + red[3][tid][1];
    float mean = S1 * (1.0f / 768.0f);
    float var = S2 * (1.0f / 768.0f) - mean * mean;
    rowstat[tid][0] = mean;
    rowstat[tid][1] = rsqrtf(var + 1e-5f);
  }
  __syncthreads();

  float gm[12], bt[12];
  #pragma unroll
  for (int nf = 0; nf < 12; ++nf) {
    gm[nf] = gamma[cbase + nf * 16 + l15];
    bt[nf] = beta[cbase + nf * 16 + l15];
  }
  #pragma unroll
  for (int mf = 0; mf < 2; ++mf) {
    #pragma unroll
    for (int r = 0; r < 4; ++r) {
      const int rl = mf * 16 + g * 4 + r;
      const int m = blk * 32 + rl;
      const int bb = m / 196;
      const int orow = bb * 197 + 1 + (m - bb * 196);
      const float mean = rowstat[rl][0], rstd = rowstat[rl][1];
      float* op = out + (size_t)orow * DTOK + cbase + l15;
      #pragma unroll
      for (int nf = 0; nf < 12; ++nf)
        op[nf * 16] = (acc[mf][nf][r] - mean) * rstd * gm[nf] + bt[nf];
    }
  }
}

extern "C" void kernel_launch(void* const* d_in, const int* in_sizes, int n_in,
                              void* d_out, int out_size, void* d_ws, size_t ws_size,
                              hipStream_t stream) {
  const float* images = (const float*)d_in[0];
  const float* W      = (const float*)d_in[1];
  const float* bias   = (const float*)d_in[2];
  const float* cls    = (const float*)d_in[3];
  const float* gamma  = (const float*)d_in[4];
  const float* beta   = (const float*)d_in[5];
  float* out = (float*)d_out;

  unsigned short* Wb = (unsigned short*)d_ws;                       // 768*768*2 B
  float* bpos = (float*)((char*)d_ws + (size_t)DTOK * DTOK * 2);    // 197*768*4 B

  conv_w<<<(DTOK * DTOK + 255) / 256, 256, 0, stream>>>(W, Wb);
  make_bpos<<<(NTOK * DTOK + 255) / 256, 256, 0, stream>>>(bias, cls, bpos);
  cls_kernel<<<1, 256, 0, stream>>>(bpos, gamma, beta, out);
  vit_main<<<MROWS / 32, 256, 0, stream>>>(images, Wb, bpos, gamma, beta, out);
}

// Round 4
// 110.266 us; speedup vs baseline: 1.7887x; 1.7887x over previous
//
#include <hip/hip_runtime.h>
#include <hip/hip_bf16.h>

// ViT embed: patchify + linear + cls + posemb + LayerNorm, fused.
// images [128,3,224,224] f32 -> out [128,197,768] f32.
// M = 128*196 = 25088 patch-rows, K = 768, N = 768.
// v4: m97-style staging. B staged via global_load_lds dwordx4 (zero VGPR)
// into double-buffered swizzled LDS (48KB/tile); A reg-cvt->bf16 LDS dbuf.
// One __syncthreads per K-step (= the vmcnt drain). XOR slot swizzle on
// both tiles (glds: linear dest + pre-swizzled SOURCE; reads swizzled).

#define IMG_B 128
#define IMG_C 3
#define IMG_HW 224
#define DTOK 768
#define NTOK 197
#define MROWS 25088

typedef __attribute__((ext_vector_type(4))) float f32x4;
typedef __attribute__((ext_vector_type(8))) short bf16x8;
typedef __attribute__((ext_vector_type(4))) short bf16x4;

__device__ __forceinline__ unsigned short f2b(float f) {
  union { float f; unsigned u; } v; v.f = f;
  unsigned u = v.u;
  return (unsigned short)((u + 0x7fffu + ((u >> 16) & 1u)) >> 16);
}

__device__ __forceinline__ void glds16(const void* g, void* l) {
  __builtin_amdgcn_global_load_lds(
      (const __attribute__((address_space(1))) unsigned int*)g,
      (__attribute__((address_space(3))) unsigned int*)l, 16, 0, 0);
}

// ---------------- setup kernels ----------------

__global__ void conv_w(const float* __restrict__ W, unsigned short* __restrict__ Wb) {
  int i = blockIdx.x * 256 + threadIdx.x;
  if (i < DTOK * DTOK) Wb[i] = f2b(W[i]);
}

__global__ void make_bpos(const float* __restrict__ bias, const float* __restrict__ cls,
                          float* __restrict__ bpos) {
  int i = blockIdx.x * 256 + threadIdx.x;
  if (i >= NTOK * DTOK) return;
  int t = i / DTOK, d = i - (i / DTOK) * DTOK;
  float expo = (float)(d & ~1) * (1.0f / (float)DTOK);
  float angle = (float)t * exp2f(-expo * 13.287712379549449f);
  float pv = (d & 1) ? cosf(angle) : sinf(angle);
  bpos[i] = pv + ((t == 0) ? cls[d] : bias[d]);
}

__global__ __launch_bounds__(256) void cls_kernel(const float* __restrict__ bpos,
                                                  const float* __restrict__ gamma,
                                                  const float* __restrict__ beta,
                                                  float* __restrict__ out) {
  __shared__ float sred[8];
  const int tid = threadIdx.x;
  float v0 = bpos[tid], v1 = bpos[tid + 256], v2 = bpos[tid + 512];
  float s1 = v0 + v1 + v2;
  float s2 = v0 * v0 + v1 * v1 + v2 * v2;
  #pragma unroll
  for (int off = 32; off >= 1; off >>= 1) {
    s1 += __shfl_xor(s1, off, 64);
    s2 += __shfl_xor(s2, off, 64);
  }
  if ((tid & 63) == 0) { sred[(tid >> 6) * 2] = s1; sred[(tid >> 6) * 2 + 1] = s2; }
  __syncthreads();
  float S1 = sred[0] + sred[2] + sred[4] + sred[6];
  float S2 = sred[1] + sred[3] + sred[5] + sred[7];
  float mean = S1 * (1.0f / 768.0f);
  float rstd = rsqrtf(S2 * (1.0f / 768.0f) - mean * mean + 1e-5f);
  float o0 = (v0 - mean) * rstd * gamma[tid] + beta[tid];
  float o1 = (v1 - mean) * rstd * gamma[tid + 256] + beta[tid + 256];
  float o2 = (v2 - mean) * rstd * gamma[tid + 512] + beta[tid + 512];
  for (int b = 0; b < IMG_B; ++b) {
    float* op = out + (size_t)b * NTOK * DTOK;
    op[tid] = o0; op[tid + 256] = o1; op[tid + 512] = o2;
  }
}

// ---------------- main fused kernel ----------------
// 512 thr / 8 waves (N-slices of 96 cols). BM=64, BK=32, 24 K-steps.
// LDS tiles in 16B "slots": row r of 32 bf16 = 4 slots; content quad q of
// row r lives at slot r*4 + (q ^ ((r>>1)&3))  -> conflict-free ds_read_b128.

__global__ __launch_bounds__(512) void vit_main(
    const float* __restrict__ images, const unsigned short* __restrict__ Wb,
    const float* __restrict__ bpos, const float* __restrict__ gamma,
    const float* __restrict__ beta, float* __restrict__ out) {
  __shared__ unsigned short Bl[2][24576];   // 2 x 48KB (768 rows x 32 bf16)
  __shared__ unsigned short Al[2][2048];    // 2 x 4KB  (64 rows x 32 bf16)
  __shared__ float red[8][64][2];
  __shared__ float rowstat[64][2];

  const int tid = threadIdx.x;
  const int wid = tid >> 6;
  const int lane = tid & 63;
  const int l15 = lane & 15;
  const int g = lane >> 4;
  const int blk = blockIdx.x;
  const int cbase = wid * 96;

  // ---- A staging role: thread -> (srow 0..63, k-quad kq 0..7) ----
  const int srow = tid >> 3;
  const int kq = tid & 7;
  const int sm = blk * 64 + srow;
  const int sb = sm / 196;
  const int sp = sm - sb * 196;
  const int spy = sp / 14, spx = sp - (sp / 14) * 14;
  const float* abase = images + (size_t)sb * (IMG_C * IMG_HW * IMG_HW) +
                       (spy * 16) * IMG_HW + spx * 16 + (kq & 3) * 4;
  const int bq = kq >> 2;
  // A LDS write index (ushorts): slot = srow*4 + ((kq>>1) ^ ((srow>>1)&3)), half = kq&1
  const int aw_idx = (srow * 4 + ((kq >> 1) ^ ((srow >> 1) & 3))) * 8 + (kq & 1) * 4;

  // ---- B staging: 6 x 16B chunks/thread. Linear dest slot d = j*512+tid;
  //      source row r = d>>2, content quad q = (d&3) ^ ((r>>1)&3) ----
  int boff[6];
  #pragma unroll
  for (int j = 0; j < 6; ++j) {
    const int d = j * 512 + tid;
    const int r = d >> 2;
    const int q = (d & 3) ^ ((r >> 1) & 3);
    boff[j] = r * DTOK + q * 8;
  }
  const int bldsbase = wid * 512;   // wave-uniform ushort idx (64 slots * 8)

  // ---- frag-read indices (swizzled): sA identical for A and B reads ----
  const int sA = g ^ ((l15 >> 1) & 3);
  const int ard = l15 * 32 + sA * 8;                // + mf*512
  const int brd = cbase * 32 + l15 * 32 + sA * 8;   // + nf*512

  f32x4 acc[4][6];
  #pragma unroll
  for (int mf = 0; mf < 4; ++mf)
    #pragma unroll
    for (int nf = 0; nf < 6; ++nf)
      acc[mf][nf] = (f32x4)(0.0f);

  // ---- prologue: stage tile 0 ----
  {
    const int v = bq;  // kstage = 0
    const float4 av = *(const float4*)(abase + (v >> 4) * 50176 + (v & 15) * 224);
    #pragma unroll
    for (int j = 0; j < 6; ++j)
      glds16(Wb + boff[j], &Bl[0][bldsbase + j * 4096]);
    union { __hip_bfloat162 h2[2]; bf16x4 v4; } u;
    u.h2[0] = __float22bfloat162_rn(make_float2(av.x, av.y));
    u.h2[1] = __float22bfloat162_rn(make_float2(av.z, av.w));
    *(bf16x4*)&Al[0][aw_idx] = u.v4;
    __syncthreads();
  }

  // ---- K-loop: 1 barrier/step; glds B(k+1) + reg-cvt A(k+1) overlap MFMA(k) ----
  for (int k = 0; k < 24; ++k) {
    const int cur = k & 1, nxt = cur ^ 1;
    float4 av;
    if (k < 23) {
      const int v = (k + 1) * 2 + bq;
      av = *(const float4*)(abase + (v >> 4) * 50176 + (v & 15) * 224);
      #pragma unroll
      for (int j = 0; j < 6; ++j)
        glds16(Wb + boff[j] + (k + 1) * 32, &Bl[nxt][bldsbase + j * 4096]);
    }

    bf16x8 afr[4];
    #pragma unroll
    for (int mf = 0; mf < 4; ++mf)
      afr[mf] = *(const bf16x8*)&Al[cur][ard + mf * 512];

    #pragma unroll
    for (int nf = 0; nf < 6; ++nf) {
      const bf16x8 bf = *(const bf16x8*)&Bl[cur][brd + nf * 512];
      #pragma unroll
      for (int mf = 0; mf < 4; ++mf)
        acc[mf][nf] =
            __builtin_amdgcn_mfma_f32_16x16x32_bf16(afr[mf], bf, acc[mf][nf], 0, 0, 0);
    }

    if (k < 23) {
      union { __hip_bfloat162 h2[2]; bf16x4 v4; } u;
      u.h2[0] = __float22bfloat162_rn(make_float2(av.x, av.y));
      u.h2[1] = __float22bfloat162_rn(make_float2(av.z, av.w));
      *(bf16x4*)&Al[nxt][aw_idx] = u.v4;
    }
    __syncthreads();   // drains glds (vmcnt) + ds_writes (lgkm); next tile ready
  }

  // ---- epilogue: +bias+pos, row LN over full 768 (all in-block) ----
  float s1[16], s2[16];
  #pragma unroll
  for (int mf = 0; mf < 4; ++mf) {
    #pragma unroll
    for (int r = 0; r < 4; ++r) {
      const int rl = mf * 16 + g * 4 + r;
      const int m = blk * 64 + rl;
      const int trow = 1 + (m % 196);
      const float* bp = bpos + (size_t)trow * DTOK + cbase + l15;
      float a1 = 0.f, a2 = 0.f;
      #pragma unroll
      for (int nf = 0; nf < 6; ++nf) {
        float val = acc[mf][nf][r] + bp[nf * 16];
        acc[mf][nf][r] = val;
        a1 += val; a2 += val * val;
      }
      s1[mf * 4 + r] = a1; s2[mf * 4 + r] = a2;
    }
  }
  #pragma unroll
  for (int off = 8; off >= 1; off >>= 1) {
    #pragma unroll
    for (int i = 0; i < 16; ++i) {
      s1[i] += __shfl_xor(s1[i], off, 64);
      s2[i] += __shfl_xor(s2[i], off, 64);
    }
  }
  if (l15 == 0) {
    #pragma unroll
    for (int mf = 0; mf < 4; ++mf)
      #pragma unroll
      for (int r = 0; r < 4; ++r) {
        const int rl = mf * 16 + g * 4 + r;
        red[wid][rl][0] = s1[mf * 4 + r];
        red[wid][rl][1] = s2[mf * 4 + r];
      }
  }
  __syncthreads();
  if (tid < 64) {
    float S1 = 0.f, S2 = 0.f;
    #pragma unroll
    for (int w = 0; w < 8; ++w) { S1 += red[w][tid][0]; S2 += red[w][tid][1]; }
    float mean = S1 * (1.0f / 768.0f);
    float var = S2 * (1.0f / 768.0f) - mean * mean;
    rowstat[tid][0] = mean;
    rowstat[tid][1] = rsqrtf(var + 1e-5f);
  }
  __syncthreads();

  float gm[6], bt[6];
  #pragma unroll
  for (int nf = 0; nf < 6; ++nf) {
    gm[nf] = gamma[cbase + nf * 16 + l15];
    bt[nf] = beta[cbase + nf * 16 + l15];
  }
  #pragma unroll
  for (int mf = 0; mf < 4; ++mf) {
    #pragma unroll
    for (int r = 0; r < 4; ++r) {
      const int rl = mf * 16 + g * 4 + r;
      const int m = blk * 64 + rl;
      const int bb = m / 196;
      const int orow = bb * 197 + 1 + (m - bb * 196);
      const float mean = rowstat[rl][0], rstd = rowstat[rl][1];
      float* op = out + (size_t)orow * DTOK + cbase + l15;
      #pragma unroll
      for (int nf = 0; nf < 6; ++nf)
        op[nf * 16] = (acc[mf][nf][r] - mean) * rstd * gm[nf] + bt[nf];
    }
  }
}

extern "C" void kernel_launch(void* const* d_in, const int* in_sizes, int n_in,
                              void* d_out, int out_size, void* d_ws, size_t ws_size,
                              hipStream_t stream) {
  const float* images = (const float*)d_in[0];
  const float* W      = (const float*)d_in[1];
  const float* bias   = (const float*)d_in[2];
  const float* cls    = (const float*)d_in[3];
  const float* gamma  = (const float*)d_in[4];
  const float* beta   = (const float*)d_in[5];
  float* out = (float*)d_out;

  unsigned short* Wb = (unsigned short*)d_ws;                       // 768*768*2 B
  float* bpos = (float*)((char*)d_ws + (size_t)DTOK * DTOK * 2);    // 197*768*4 B

  conv_w<<<(DTOK * DTOK + 255) / 256, 256, 0, stream>>>(W, Wb);
  make_bpos<<<(NTOK * DTOK + 255) / 256, 256, 0, stream>>>(bias, cls, bpos);
  cls_kernel<<<1, 256, 0, stream>>>(bpos, gamma, beta, out);
  vit_main<<<MROWS / 64, 512, 0, stream>>>(images, Wb, bpos, gamma, beta, out);
}